// Round 5
// baseline (270.294 us; speedup 1.0000x reference)
//
#include <hip/hip_runtime.h>
#include <hip/hip_bf16.h>
#include <math.h>

#define NN 50000
#define DD 128
#define CC 64
#define EE 800000
#define IND 384

typedef __attribute__((ext_vector_type(8))) short s8v;
typedef __attribute__((ext_vector_type(8))) unsigned short u8v;
typedef __attribute__((ext_vector_type(8))) float f8v;
typedef __attribute__((ext_vector_type(4))) float f4v;

static __device__ __forceinline__ unsigned short f2bf(float f) {
  __hip_bfloat16 b = __float2bfloat16(f);
  return *reinterpret_cast<unsigned short*>(&b);
}
static __device__ __forceinline__ float bf2f(unsigned short u) {
  __hip_bfloat16 b = *reinterpret_cast<__hip_bfloat16*>(&u);
  return __bfloat162float(b);
}
static __device__ __forceinline__ float blo(unsigned int u) {
  return __uint_as_float(u << 16);
}
static __device__ __forceinline__ float bhi(unsigned int u) {
  return __uint_as_float(u & 0xffff0000u);
}
static __device__ __forceinline__ s8v zero8() {
  s8v v = {0, 0, 0, 0, 0, 0, 0, 0};
  return v;
}

// ---------------- per-node logmap scale factors ----------------
__global__ __launch_bounds__(256) void k_scal(const float* __restrict__ xH,
                                              const float* __restrict__ xS,
                                              float* __restrict__ ch,
                                              float* __restrict__ cs) {
  int gw = (blockIdx.x * 256 + threadIdx.x) >> 6;
  int lane = threadIdx.x & 63;
  if (gw >= NN) return;
  const float2* h2 = (const float2*)(xH) + (size_t)gw * 64;
  float2 vh = h2[lane];
  float ssh = vh.x * vh.x + vh.y * vh.y;
  if (lane == 0) ssh -= vh.x * vh.x;
#pragma unroll
  for (int off = 32; off; off >>= 1) ssh += __shfl_down(ssh, off);
  const float2* s2 = (const float2*)(xS) + (size_t)gw * 64;
  float2 vs = s2[lane];
  float sss = vs.x * vs.x + vs.y * vs.y;
  if (lane == 0) sss -= vs.x * vs.x;
#pragma unroll
  for (int off = 32; off; off >>= 1) sss += __shfl_down(sss, off);
  if (lane == 0) {
    float nrh = sqrtf(ssh);
    float dist = acoshf(fmaxf(vh.x, 1.0f));
    ch[gw] = dist / fmaxf(nrh, 1e-12f);
    float nrs = sqrtf(sss);
    float th = acosf(fminf(fmaxf(vs.x, -1.0f), 1.0f));
    cs[gw] = th / fmaxf(nrs, 1e-12f);
  }
}

// ---------------- edge in-degree count ----------------
__global__ __launch_bounds__(256) void k_count(const int* __restrict__ dst,
                                               int* __restrict__ cnt) {
  int e = blockIdx.x * 256 + threadIdx.x;
  if (e < EE) atomicAdd(&cnt[dst[e]], 1);
}

// ---------------- hierarchical exclusive scan ----------------
__global__ __launch_bounds__(1024) void k_scan1(const int* __restrict__ cnt,
                                                int* __restrict__ rowstart,
                                                float* __restrict__ dinv,
                                                int* __restrict__ bsum) {
  __shared__ int wsum[16];
  int tid = threadIdx.x;
  int wave = tid >> 6, lane = tid & 63;
  int i = blockIdx.x * 1024 + tid;
  int v = (i < NN) ? cnt[i] : 0;
  int x = v;
#pragma unroll
  for (int off = 1; off < 64; off <<= 1) {
    int t = __shfl_up(x, off);
    if (lane >= off) x += t;
  }
  if (lane == 63) wsum[wave] = x;
  __syncthreads();
  if (wave == 0 && lane < 16) {
    int y = wsum[lane];
#pragma unroll
    for (int off = 1; off < 16; off <<= 1) {
      int t = __shfl_up(y, off);
      if (lane >= off) y += t;
    }
    wsum[lane] = y;
  }
  __syncthreads();
  int ex = (wave ? wsum[wave - 1] : 0) + x - v;
  if (i < NN) {
    rowstart[i] = ex;
    dinv[i] = 1.0f / sqrtf((float)(v + 1));
  }
  if (tid == 1023) bsum[blockIdx.x] = wsum[15];
}

__global__ __launch_bounds__(64) void k_scan2(int* __restrict__ bsum,
                                              int* __restrict__ rowstart,
                                              int nb) {
  int lane = threadIdx.x;
  int v = (lane < nb) ? bsum[lane] : 0;
  int x = v;
#pragma unroll
  for (int off = 1; off < 64; off <<= 1) {
    int t = __shfl_up(x, off);
    if (lane >= off) x += t;
  }
  if (lane < nb) bsum[lane] = x - v;
  if (lane == 0) rowstart[NN] = EE;
}

__global__ __launch_bounds__(1024) void k_scan3(int* __restrict__ rowstart,
                                                int* __restrict__ cursor,
                                                const int* __restrict__ bsum) {
  int i = blockIdx.x * 1024 + threadIdx.x;
  if (i < NN) {
    int r = rowstart[i] + bsum[blockIdx.x];
    rowstart[i] = r;
    cursor[i] = r;
  }
}

// ---------------- CSR placement ----------------
__global__ __launch_bounds__(256) void k_place(const int* __restrict__ src,
                                               const int* __restrict__ dst,
                                               int* __restrict__ cursor,
                                               int* __restrict__ col) {
  int e = blockIdx.x * 256 + threadIdx.x;
  if (e < EE) {
    int d = dst[e];
    int p = atomicAdd(&cursor[d], 1);
    col[p] = src[e];
  }
}

// ---------------- W transpose + bf16 hi/lo split: Wt[128][384] ----------------
__global__ __launch_bounds__(256) void k_wprep(const float* __restrict__ W,
                                               unsigned short* __restrict__ Wth,
                                               unsigned short* __restrict__ Wtl) {
  int flat = blockIdx.x * 256 + threadIdx.x;
  if (flat >= IND * DD) return;
  int n = flat / IND;
  int k = flat - n * IND;
  float v = W[(size_t)k * DD + n];
  unsigned short hi = f2bf(v);
  unsigned short lo = f2bf(v - bf2f(hi));
  Wth[(size_t)n * IND + k] = hi;
  Wtl[(size_t)n * IND + k] = lo;
}

// ---- MFMA GEMM, register-direct A (no LDS, no barriers) ----
// block = 4 waves (2 row-waves x 2 col-waves); wave = 32 rows x 64 cols
__global__ __launch_bounds__(256) void k_gemm(const float* __restrict__ xE,
                                              const float* __restrict__ xH,
                                              const float* __restrict__ xS,
                                              const float* __restrict__ ch,
                                              const float* __restrict__ cs,
                                              const unsigned short* __restrict__ Wth,
                                              const unsigned short* __restrict__ Wtl,
                                              unsigned short* __restrict__ h) {
  int tid = threadIdx.x;
  int lane = tid & 63;
  int wid = tid >> 6;
  int wr = wid >> 1, wc = wid & 1;
  int bm0 = blockIdx.x * 64 + wr * 32;  // wave row base
  int c0 = wc * 64;
  int l15 = lane & 15;
  int lhi = lane >> 4;

  f4v acc[2][4];
#pragma unroll
  for (int m = 0; m < 2; ++m)
#pragma unroll
    for (int nf = 0; nf < 4; ++nf) acc[m][nf] = f4v{0.f, 0.f, 0.f, 0.f};

#pragma unroll
  for (int kb = 0; kb < IND; kb += 32) {
    int sec = kb >> 7;                 // 0:E 1:H 2:S
    int off = (kb & 127) + lhi * 8;    // col within section for this lane
    const float* __restrict__ src = (sec == 0) ? xE : (sec == 1) ? xH : xS;
    s8v ah[2], al[2];
#pragma unroll
    for (int m = 0; m < 2; ++m) {
      int node = bm0 + m * 16 + l15;
      f8v v;
      float scale;
      if (node < NN) {
        v = *reinterpret_cast<const f8v*>(&src[(size_t)node * DD + off]);
        scale = (sec == 0) ? 1.0f : (sec == 1) ? ch[node] : cs[node];
      } else {
        v = f8v{0.f, 0.f, 0.f, 0.f, 0.f, 0.f, 0.f, 0.f};
        scale = 0.f;
      }
#pragma unroll
      for (int j = 0; j < 8; ++j) v[j] *= scale;
      if (sec > 0 && off == 0) v[0] = 0.f;  // logmap zero column
      u8v hh, ll;
#pragma unroll
      for (int j = 0; j < 8; ++j) {
        unsigned short hi = f2bf(v[j]);
        hh[j] = hi;
        ll[j] = f2bf(v[j] - bf2f(hi));
      }
      ah[m] = *reinterpret_cast<s8v*>(&hh);
      al[m] = *reinterpret_cast<s8v*>(&ll);
    }
    int kk = kb + lhi * 8;
#pragma unroll
    for (int nf = 0; nf < 4; ++nf) {
      int n = c0 + nf * 16 + l15;
      s8v bhi8 = *reinterpret_cast<const s8v*>(&Wth[(size_t)n * IND + kk]);
      s8v blo8 = *reinterpret_cast<const s8v*>(&Wtl[(size_t)n * IND + kk]);
#pragma unroll
      for (int m = 0; m < 2; ++m) {
        acc[m][nf] = __builtin_amdgcn_mfma_f32_16x16x32_bf16(ah[m], bhi8, acc[m][nf], 0, 0, 0);
        acc[m][nf] = __builtin_amdgcn_mfma_f32_16x16x32_bf16(al[m], bhi8, acc[m][nf], 0, 0, 0);
        acc[m][nf] = __builtin_amdgcn_mfma_f32_16x16x32_bf16(ah[m], blo8, acc[m][nf], 0, 0, 0);
      }
    }
  }
#pragma unroll
  for (int m = 0; m < 2; ++m)
#pragma unroll
    for (int nf = 0; nf < 4; ++nf) {
      int colx = c0 + nf * 16 + l15;
      int rowb = bm0 + m * 16 + lhi * 4;
#pragma unroll
      for (int j = 0; j < 4; ++j) {
        int node = rowb + j;
        if (node < NN) h[(size_t)node * DD + colx] = f2bf(acc[m][nf][j]);
      }
    }
}

// ---------------- normalize class embeddings -> bf16 hi/lo [64][128] ----------
__global__ __launch_bounds__(256) void k_cprep(const float* __restrict__ cls,
                                               unsigned int* __restrict__ clsh,
                                               unsigned int* __restrict__ clsl) {
  int wave = threadIdx.x >> 6, lane = threadIdx.x & 63;
  for (int c = wave; c < CC; c += 4) {
    const float2* r2 = (const float2*)(cls + (size_t)c * DD);
    float2 v = r2[lane];
    float ss = v.x * v.x + v.y * v.y;
#pragma unroll
    for (int off = 32; off; off >>= 1) ss += __shfl_xor(ss, off);
    float inv = 1.0f / fmaxf(sqrtf(ss), 1e-8f);
    float nx = v.x * inv, ny = v.y * inv;
    unsigned short hx = f2bf(nx), hy = f2bf(ny);
    unsigned short lx = f2bf(nx - bf2f(hx)), ly = f2bf(ny - bf2f(hy));
    clsh[c * 64 + lane] = (unsigned int)hx | ((unsigned int)hy << 16);
    clsl[c * 64 + lane] = (unsigned int)lx | ((unsigned int)ly << 16);
  }
}

// ---- CSR aggregation + in-wave normalize -> xn bf16 hi/lo ----
__global__ __launch_bounds__(256) void k_aggn(const unsigned short* __restrict__ h,
                                              const int* __restrict__ rowstart,
                                              const int* __restrict__ col,
                                              const float* __restrict__ dinv,
                                              const float* __restrict__ b,
                                              unsigned int* __restrict__ xnh,
                                              unsigned int* __restrict__ xnl) {
  int node = (blockIdx.x * 256 + threadIdx.x) >> 6;
  int lane = threadIdx.x & 63;
  if (node >= NN) return;

  const unsigned int* h2 = (const unsigned int*)h;
  float dv = dinv[node];
  unsigned int hv = h2[(size_t)node * 64 + lane];
  float ax = dv * blo(hv), ay = dv * bhi(hv);
  int s = rowstart[node], e = rowstart[node + 1];
  int j = s;
  // 16-deep batch: max loads in flight (latency-bound loop)
  for (; j + 15 < e; j += 16) {
    int cc[16];
    float ff[16];
    unsigned int vv[16];
#pragma unroll
    for (int q = 0; q < 16; ++q) cc[q] = col[j + q];
#pragma unroll
    for (int q = 0; q < 16; ++q) ff[q] = dinv[cc[q]];
#pragma unroll
    for (int q = 0; q < 16; ++q) vv[q] = h2[(size_t)cc[q] * 64 + lane];
#pragma unroll
    for (int q = 0; q < 16; ++q) {
      ax += ff[q] * blo(vv[q]);
      ay += ff[q] * bhi(vv[q]);
    }
  }
  for (; j + 3 < e; j += 4) {
    int c0_ = col[j], c1_ = col[j + 1], c2_ = col[j + 2], c3_ = col[j + 3];
    float f0 = dinv[c0_], f1 = dinv[c1_], f2 = dinv[c2_], f3 = dinv[c3_];
    unsigned int v0 = h2[(size_t)c0_ * 64 + lane];
    unsigned int v1 = h2[(size_t)c1_ * 64 + lane];
    unsigned int v2 = h2[(size_t)c2_ * 64 + lane];
    unsigned int v3 = h2[(size_t)c3_ * 64 + lane];
    ax += f0 * blo(v0) + f1 * blo(v1) + f2 * blo(v2) + f3 * blo(v3);
    ay += f0 * bhi(v0) + f1 * bhi(v1) + f2 * bhi(v2) + f3 * bhi(v3);
  }
  for (; j < e; ++j) {
    int sc = col[j];
    float f = dinv[sc];
    unsigned int v = h2[(size_t)sc * 64 + lane];
    ax += f * blo(v);
    ay += f * bhi(v);
  }
  const float2* b2 = (const float2*)b;
  float2 bb = b2[lane];
  float rx = dv * ax + bb.x;
  float ry = dv * ay + bb.y;
  float ss = rx * rx + ry * ry;
#pragma unroll
  for (int off = 32; off; off >>= 1) ss += __shfl_xor(ss, off);
  float inv = 1.0f / fmaxf(sqrtf(ss), 1e-8f);
  float nx = rx * inv, ny = ry * inv;
  unsigned short hx = f2bf(nx), hy = f2bf(ny);
  unsigned short lx = f2bf(nx - bf2f(hx)), ly = f2bf(ny - bf2f(hy));
  xnh[(size_t)node * 64 + lane] = (unsigned int)hx | ((unsigned int)hy << 16);
  xnl[(size_t)node * 64 + lane] = (unsigned int)lx | ((unsigned int)ly << 16);
}

// ---- classifier MFMA GEMM: out = xn @ clsn^T (hi/lo 3-term) ----
__global__ __launch_bounds__(256) void k_outg(const unsigned short* __restrict__ xnh,
                                              const unsigned short* __restrict__ xnl,
                                              const unsigned short* __restrict__ clsh,
                                              const unsigned short* __restrict__ clsl,
                                              float* __restrict__ out) {
  int tid = threadIdx.x;
  int lane = tid & 63;
  int wid = tid >> 6;
  int l15 = lane & 15, lhi = lane >> 4;
  int bm0 = blockIdx.x * 128 + wid * 32;

  f4v acc[2][4];
#pragma unroll
  for (int m = 0; m < 2; ++m)
#pragma unroll
    for (int nf = 0; nf < 4; ++nf) acc[m][nf] = f4v{0.f, 0.f, 0.f, 0.f};

#pragma unroll
  for (int ks = 0; ks < 4; ++ks) {
    s8v ah[2], al[2];
#pragma unroll
    for (int m = 0; m < 2; ++m) {
      int row = bm0 + m * 16 + l15;
      if (row < NN) {
        ah[m] = *reinterpret_cast<const s8v*>(&xnh[(size_t)row * DD + ks * 32 + lhi * 8]);
        al[m] = *reinterpret_cast<const s8v*>(&xnl[(size_t)row * DD + ks * 32 + lhi * 8]);
      } else {
        ah[m] = zero8();
        al[m] = zero8();
      }
    }
#pragma unroll
    for (int nf = 0; nf < 4; ++nf) {
      int n = nf * 16 + l15;
      s8v bh = *reinterpret_cast<const s8v*>(&clsh[(size_t)n * DD + ks * 32 + lhi * 8]);
      s8v bl = *reinterpret_cast<const s8v*>(&clsl[(size_t)n * DD + ks * 32 + lhi * 8]);
#pragma unroll
      for (int m = 0; m < 2; ++m) {
        acc[m][nf] = __builtin_amdgcn_mfma_f32_16x16x32_bf16(ah[m], bh, acc[m][nf], 0, 0, 0);
        acc[m][nf] = __builtin_amdgcn_mfma_f32_16x16x32_bf16(al[m], bh, acc[m][nf], 0, 0, 0);
        acc[m][nf] = __builtin_amdgcn_mfma_f32_16x16x32_bf16(ah[m], bl, acc[m][nf], 0, 0, 0);
      }
    }
  }
#pragma unroll
  for (int m = 0; m < 2; ++m)
#pragma unroll
    for (int nf = 0; nf < 4; ++nf) {
      int colx = nf * 16 + l15;
      int rowb = bm0 + m * 16 + lhi * 4;
#pragma unroll
      for (int j = 0; j < 4; ++j) {
        int row = rowb + j;
        if (row < NN) out[(size_t)row * CC + colx] = acc[m][nf][j];
      }
    }
}

extern "C" void kernel_launch(void* const* d_in, const int* in_sizes, int n_in,
                              void* d_out, int out_size, void* d_ws, size_t ws_size,
                              hipStream_t stream) {
  const float* xE = (const float*)d_in[0];
  const float* xH = (const float*)d_in[1];
  const float* xS = (const float*)d_in[2];
  const int* ei = (const int*)d_in[3];
  const float* W = (const float*)d_in[4];
  const float* b = (const float*)d_in[5];
  const float* cls = (const float*)d_in[6];
  float* out = (float*)d_out;

  char* ws = (char*)d_ws;
  size_t off = 0;
  auto alloc = [&](size_t bytes) {
    void* p = ws + off;
    off = (off + bytes + 255) & ~(size_t)255;
    return p;
  };
  unsigned short* h = (unsigned short*)alloc((size_t)NN * DD * 2);
  unsigned int* xnh = (unsigned int*)alloc((size_t)NN * 64 * 4);
  unsigned int* xnl = (unsigned int*)alloc((size_t)NN * 64 * 4);
  float* dinv = (float*)alloc((size_t)NN * 4);
  float* chv = (float*)alloc((size_t)NN * 4);
  float* csv = (float*)alloc((size_t)NN * 4);
  int* cnt = (int*)alloc((size_t)NN * 4);
  int* rowst = (int*)alloc((size_t)(NN + 1) * 4);
  int* cursor = (int*)alloc((size_t)NN * 4);
  int* col = (int*)alloc((size_t)EE * 4);
  unsigned short* Wth = (unsigned short*)alloc((size_t)DD * IND * 2);
  unsigned short* Wtl = (unsigned short*)alloc((size_t)DD * IND * 2);
  unsigned int* clsh = (unsigned int*)alloc((size_t)CC * 64 * 4);
  unsigned int* clsl = (unsigned int*)alloc((size_t)CC * 64 * 4);
  int* bsum = (int*)alloc(64 * 4);

  const int* esrc = ei;
  const int* edst = ei + EE;
  const int NB = (NN + 1023) / 1024;

  hipMemsetAsync(cnt, 0, (size_t)NN * 4, stream);
  k_scal<<<(NN + 3) / 4, 256, 0, stream>>>(xH, xS, chv, csv);
  k_count<<<(EE + 255) / 256, 256, 0, stream>>>(edst, cnt);
  k_scan1<<<NB, 1024, 0, stream>>>(cnt, rowst, dinv, bsum);
  k_scan2<<<1, 64, 0, stream>>>(bsum, rowst, NB);
  k_scan3<<<NB, 1024, 0, stream>>>(rowst, cursor, bsum);
  k_place<<<(EE + 255) / 256, 256, 0, stream>>>(esrc, edst, cursor, col);
  k_wprep<<<(IND * DD + 255) / 256, 256, 0, stream>>>(W, Wth, Wtl);
  k_gemm<<<(NN + 63) / 64, 256, 0, stream>>>(xE, xH, xS, chv, csv, Wth, Wtl, h);
  k_cprep<<<1, 256, 0, stream>>>(cls, clsh, clsl);
  k_aggn<<<(NN + 3) / 4, 256, 0, stream>>>(h, rowst, col, dinv, b, xnh, xnl);
  k_outg<<<(NN + 127) / 128, 256, 0, stream>>>((const unsigned short*)xnh,
                                               (const unsigned short*)xnl,
                                               (const unsigned short*)clsh,
                                               (const unsigned short*)clsl, out);
}

// Round 7
// 255.537 us; speedup vs baseline: 1.0577x; 1.0577x over previous
//
#include <hip/hip_runtime.h>
#include <hip/hip_bf16.h>
#include <math.h>

#define NN 50000
#define DD 128
#define CC 64
#define EE 800000
#define IND 384

typedef __attribute__((ext_vector_type(8))) short s8v;
typedef __attribute__((ext_vector_type(8))) unsigned short u8v;
typedef __attribute__((ext_vector_type(8))) float f8v;
typedef __attribute__((ext_vector_type(4))) float f4v;

static __device__ __forceinline__ unsigned short f2bf(float f) {
  __hip_bfloat16 b = __float2bfloat16(f);
  return *reinterpret_cast<unsigned short*>(&b);
}
static __device__ __forceinline__ float bf2f(unsigned short u) {
  __hip_bfloat16 b = *reinterpret_cast<__hip_bfloat16*>(&u);
  return __bfloat162float(b);
}
static __device__ __forceinline__ float blo(unsigned int u) {
  return __uint_as_float(u << 16);
}
static __device__ __forceinline__ float bhi(unsigned int u) {
  return __uint_as_float(u & 0xffff0000u);
}
static __device__ __forceinline__ s8v zero8() {
  s8v v = {0, 0, 0, 0, 0, 0, 0, 0};
  return v;
}

// ---------------- edge in-degree count ----------------
__global__ __launch_bounds__(256) void k_count(const int* __restrict__ dst,
                                               int* __restrict__ cnt) {
  int e = blockIdx.x * 256 + threadIdx.x;
  if (e < EE) atomicAdd(&cnt[dst[e]], 1);
}

// ---------------- hierarchical exclusive scan ----------------
__global__ __launch_bounds__(1024) void k_scan1(const int* __restrict__ cnt,
                                                int* __restrict__ rowstart,
                                                float* __restrict__ dinv,
                                                int* __restrict__ bsum) {
  __shared__ int wsum[16];
  int tid = threadIdx.x;
  int wave = tid >> 6, lane = tid & 63;
  int i = blockIdx.x * 1024 + tid;
  int v = (i < NN) ? cnt[i] : 0;
  int x = v;
#pragma unroll
  for (int off = 1; off < 64; off <<= 1) {
    int t = __shfl_up(x, off);
    if (lane >= off) x += t;
  }
  if (lane == 63) wsum[wave] = x;
  __syncthreads();
  if (wave == 0 && lane < 16) {
    int y = wsum[lane];
#pragma unroll
    for (int off = 1; off < 16; off <<= 1) {
      int t = __shfl_up(y, off);
      if (lane >= off) y += t;
    }
    wsum[lane] = y;
  }
  __syncthreads();
  int ex = (wave ? wsum[wave - 1] : 0) + x - v;
  if (i < NN) {
    rowstart[i] = ex;
    dinv[i] = 1.0f / sqrtf((float)(v + 1));
  }
  if (tid == 1023) bsum[blockIdx.x] = wsum[15];
}

__global__ __launch_bounds__(64) void k_scan2(int* __restrict__ bsum,
                                              int* __restrict__ rowstart,
                                              int nb) {
  int lane = threadIdx.x;
  int v = (lane < nb) ? bsum[lane] : 0;
  int x = v;
#pragma unroll
  for (int off = 1; off < 64; off <<= 1) {
    int t = __shfl_up(x, off);
    if (lane >= off) x += t;
  }
  if (lane < nb) bsum[lane] = x - v;
  if (lane == 0) rowstart[NN] = EE;
}

__global__ __launch_bounds__(1024) void k_scan3(int* __restrict__ rowstart,
                                                int* __restrict__ cursor,
                                                const int* __restrict__ bsum) {
  int i = blockIdx.x * 1024 + threadIdx.x;
  if (i < NN) {
    int r = rowstart[i] + bsum[blockIdx.x];
    rowstart[i] = r;
    cursor[i] = r;
  }
}

// ---------------- CSR placement ----------------
__global__ __launch_bounds__(256) void k_place(const int* __restrict__ src,
                                               const int* __restrict__ dst,
                                               int* __restrict__ cursor,
                                               int* __restrict__ col) {
  int e = blockIdx.x * 256 + threadIdx.x;
  if (e < EE) {
    int d = dst[e];
    int p = atomicAdd(&cursor[d], 1);
    col[p] = src[e];
  }
}

// ---------------- W transpose + bf16 hi/lo split: Wt[128][384] ----------------
__global__ __launch_bounds__(256) void k_wprep(const float* __restrict__ W,
                                               unsigned short* __restrict__ Wth,
                                               unsigned short* __restrict__ Wtl) {
  int flat = blockIdx.x * 256 + threadIdx.x;
  if (flat >= IND * DD) return;
  int n = flat / IND;
  int k = flat - n * IND;
  float v = W[(size_t)k * DD + n];
  unsigned short hi = f2bf(v);
  unsigned short lo = f2bf(v - bf2f(hi));
  Wth[(size_t)n * IND + k] = hi;
  Wtl[(size_t)n * IND + k] = lo;
}

// ---- MFMA GEMM with fused logmap + dinv-scaled bf16 output ----
// block = 32 rows x 128 cols, 4 waves (2 row x 2 col); wave = 16 rows x 64 cols.
// Norm over x[1:] computed by DIRECT sum (element 0 predicated out before
// squaring) -- no big-minus-big cancellation (round-6 bug).
__global__ __launch_bounds__(256, 2) void k_gemm(const float* __restrict__ xE,
                                                 const float* __restrict__ xH,
                                                 const float* __restrict__ xS,
                                                 const unsigned short* __restrict__ Wth,
                                                 const unsigned short* __restrict__ Wtl,
                                                 const float* __restrict__ dinv,
                                                 unsigned short* __restrict__ h) {
  int tid = threadIdx.x;
  int lane = tid & 63;
  int wid = tid >> 6;
  int wr = wid >> 1, wc = wid & 1;
  int row0 = blockIdx.x * 32 + wr * 16;
  int c0 = wc * 64;
  int l15 = lane & 15;
  int lhi = lane >> 4;
  int node = row0 + l15;
  bool valid = node < NN;
  size_t rowbase = (size_t)node * DD;

  f4v acc[4];
#pragma unroll
  for (int nf = 0; nf < 4; ++nf) acc[nf] = f4v{0.f, 0.f, 0.f, 0.f};

#pragma unroll
  for (int sec = 0; sec < 3; ++sec) {
    const float* __restrict__ src = (sec == 0) ? xE : (sec == 1) ? xH : xS;
    f8v v[4];
#pragma unroll
    for (int q = 0; q < 4; ++q) {
      if (valid)
        v[q] = *reinterpret_cast<const f8v*>(&src[rowbase + q * 32 + lhi * 8]);
      else
        v[q] = f8v{0.f, 0.f, 0.f, 0.f, 0.f, 0.f, 0.f, 0.f};
    }
    float scale = 1.0f;
    if (sec > 0) {
      // direct sum over x[1:]: predicate element 0 to zero BEFORE squaring
      float ss = 0.f;
#pragma unroll
      for (int q = 0; q < 4; ++q)
#pragma unroll
        for (int j = 0; j < 8; ++j) {
          float xx = v[q][j];
          if (q == 0 && j == 0) xx = (lhi == 0) ? 0.f : xx;
          ss += xx * xx;
        }
      float e0 = __shfl(v[0][0], l15);  // row's element 0 (lane l15 has lhi=0)
      ss += __shfl_xor(ss, 16);
      ss += __shfl_xor(ss, 32);
      float nr = sqrtf(fmaxf(ss, 0.f));
      float d = (sec == 1) ? acoshf(fmaxf(e0, 1.0f))
                           : acosf(fminf(fmaxf(e0, -1.0f), 1.0f));
      scale = d / fmaxf(nr, 1e-12f);
    }
    s8v ah[4], al[4];
#pragma unroll
    for (int q = 0; q < 4; ++q) {
      f8v t;
#pragma unroll
      for (int j = 0; j < 8; ++j) t[j] = v[q][j] * scale;
      if (sec > 0 && q == 0 && lhi == 0) t[0] = 0.f;  // logmap zero column
      u8v hh, ll;
#pragma unroll
      for (int j = 0; j < 8; ++j) {
        unsigned short hi = f2bf(t[j]);
        hh[j] = hi;
        ll[j] = f2bf(t[j] - bf2f(hi));
      }
      ah[q] = *reinterpret_cast<s8v*>(&hh);
      al[q] = *reinterpret_cast<s8v*>(&ll);
    }
#pragma unroll
    for (int q = 0; q < 4; ++q) {
      int kk = sec * 128 + q * 32 + lhi * 8;
#pragma unroll
      for (int nf = 0; nf < 4; ++nf) {
        int n = c0 + nf * 16 + l15;
        s8v bh = *reinterpret_cast<const s8v*>(&Wth[(size_t)n * IND + kk]);
        s8v bl = *reinterpret_cast<const s8v*>(&Wtl[(size_t)n * IND + kk]);
        acc[nf] = __builtin_amdgcn_mfma_f32_16x16x32_bf16(ah[q], bh, acc[nf], 0, 0, 0);
        acc[nf] = __builtin_amdgcn_mfma_f32_16x16x32_bf16(al[q], bh, acc[nf], 0, 0, 0);
        acc[nf] = __builtin_amdgcn_mfma_f32_16x16x32_bf16(ah[q], bl, acc[nf], 0, 0, 0);
      }
    }
  }
  // epilogue: fold dinv into h (h_scaled = dinv[row] * h[row])
  float dv[4];
#pragma unroll
  for (int j = 0; j < 4; ++j) {
    int nodeo = row0 + lhi * 4 + j;
    dv[j] = (nodeo < NN) ? dinv[nodeo] : 0.f;
  }
#pragma unroll
  for (int nf = 0; nf < 4; ++nf) {
    int colx = c0 + nf * 16 + l15;
#pragma unroll
    for (int j = 0; j < 4; ++j) {
      int nodeo = row0 + lhi * 4 + j;
      if (nodeo < NN) h[(size_t)nodeo * DD + colx] = f2bf(acc[nf][j] * dv[j]);
    }
  }
}

// ---------------- normalize class embeddings -> bf16 hi/lo [64][128] ----------
__global__ __launch_bounds__(256) void k_cprep(const float* __restrict__ cls,
                                               unsigned int* __restrict__ clsh,
                                               unsigned int* __restrict__ clsl) {
  int wave = threadIdx.x >> 6, lane = threadIdx.x & 63;
  for (int c = wave; c < CC; c += 4) {
    const float2* r2 = (const float2*)(cls + (size_t)c * DD);
    float2 v = r2[lane];
    float ss = v.x * v.x + v.y * v.y;
#pragma unroll
    for (int off = 32; off; off >>= 1) ss += __shfl_xor(ss, off);
    float inv = 1.0f / fmaxf(sqrtf(ss), 1e-8f);
    float nx = v.x * inv, ny = v.y * inv;
    unsigned short hx = f2bf(nx), hy = f2bf(ny);
    unsigned short lx = f2bf(nx - bf2f(hx)), ly = f2bf(ny - bf2f(hy));
    clsh[c * 64 + lane] = (unsigned int)hx | ((unsigned int)hy << 16);
    clsl[c * 64 + lane] = (unsigned int)lx | ((unsigned int)ly << 16);
  }
}

// ---- CSR aggregation (h pre-scaled by dinv) + normalize -> xn bf16 hi/lo ----
__global__ __launch_bounds__(256) void k_aggn(const unsigned short* __restrict__ h,
                                              const int* __restrict__ rowstart,
                                              const int* __restrict__ col,
                                              const float* __restrict__ dinv,
                                              const float* __restrict__ b,
                                              unsigned int* __restrict__ xnh,
                                              unsigned int* __restrict__ xnl) {
  int node = (blockIdx.x * 256 + threadIdx.x) >> 6;
  int lane = threadIdx.x & 63;
  if (node >= NN) return;

  const unsigned int* h2 = (const unsigned int*)h;
  float dv = dinv[node];
  unsigned int hv = h2[(size_t)node * 64 + lane];  // = dinv[node]*h[node]
  float ax = blo(hv), ay = bhi(hv);
  int s = rowstart[node], e = rowstart[node + 1];
  int j = s;
  for (; j + 15 < e; j += 16) {
    int cc[16];
    unsigned int vv[16];
#pragma unroll
    for (int q = 0; q < 16; ++q) cc[q] = col[j + q];
#pragma unroll
    for (int q = 0; q < 16; ++q) vv[q] = h2[(size_t)cc[q] * 64 + lane];
#pragma unroll
    for (int q = 0; q < 16; ++q) {
      ax += blo(vv[q]);
      ay += bhi(vv[q]);
    }
  }
  for (; j + 3 < e; j += 4) {
    int c0_ = col[j], c1_ = col[j + 1], c2_ = col[j + 2], c3_ = col[j + 3];
    unsigned int v0 = h2[(size_t)c0_ * 64 + lane];
    unsigned int v1 = h2[(size_t)c1_ * 64 + lane];
    unsigned int v2 = h2[(size_t)c2_ * 64 + lane];
    unsigned int v3 = h2[(size_t)c3_ * 64 + lane];
    ax += blo(v0) + blo(v1) + blo(v2) + blo(v3);
    ay += bhi(v0) + bhi(v1) + bhi(v2) + bhi(v3);
  }
  for (; j < e; ++j) {
    unsigned int v = h2[(size_t)col[j] * 64 + lane];
    ax += blo(v);
    ay += bhi(v);
  }
  const float2* b2 = (const float2*)b;
  float2 bb = b2[lane];
  float rx = dv * ax + bb.x;
  float ry = dv * ay + bb.y;
  float ss = rx * rx + ry * ry;
#pragma unroll
  for (int off = 32; off; off >>= 1) ss += __shfl_xor(ss, off);
  float inv = 1.0f / fmaxf(sqrtf(ss), 1e-8f);
  float nx = rx * inv, ny = ry * inv;
  unsigned short hx = f2bf(nx), hy = f2bf(ny);
  unsigned short lx = f2bf(nx - bf2f(hx)), ly = f2bf(ny - bf2f(hy));
  xnh[(size_t)node * 64 + lane] = (unsigned int)hx | ((unsigned int)hy << 16);
  xnl[(size_t)node * 64 + lane] = (unsigned int)lx | ((unsigned int)ly << 16);
}

// ---- classifier MFMA GEMM: out = xn @ clsn^T (hi/lo 3-term) ----
__global__ __launch_bounds__(256) void k_outg(const unsigned short* __restrict__ xnh,
                                              const unsigned short* __restrict__ xnl,
                                              const unsigned short* __restrict__ clsh,
                                              const unsigned short* __restrict__ clsl,
                                              float* __restrict__ out) {
  int tid = threadIdx.x;
  int lane = tid & 63;
  int wid = tid >> 6;
  int l15 = lane & 15, lhi = lane >> 4;
  int bm0 = blockIdx.x * 128 + wid * 32;

  f4v acc[2][4];
#pragma unroll
  for (int m = 0; m < 2; ++m)
#pragma unroll
    for (int nf = 0; nf < 4; ++nf) acc[m][nf] = f4v{0.f, 0.f, 0.f, 0.f};

#pragma unroll
  for (int ks = 0; ks < 4; ++ks) {
    s8v ah[2], al[2];
#pragma unroll
    for (int m = 0; m < 2; ++m) {
      int row = bm0 + m * 16 + l15;
      if (row < NN) {
        ah[m] = *reinterpret_cast<const s8v*>(&xnh[(size_t)row * DD + ks * 32 + lhi * 8]);
        al[m] = *reinterpret_cast<const s8v*>(&xnl[(size_t)row * DD + ks * 32 + lhi * 8]);
      } else {
        ah[m] = zero8();
        al[m] = zero8();
      }
    }
#pragma unroll
    for (int nf = 0; nf < 4; ++nf) {
      int n = nf * 16 + l15;
      s8v bh = *reinterpret_cast<const s8v*>(&clsh[(size_t)n * DD + ks * 32 + lhi * 8]);
      s8v bl = *reinterpret_cast<const s8v*>(&clsl[(size_t)n * DD + ks * 32 + lhi * 8]);
#pragma unroll
      for (int m = 0; m < 2; ++m) {
        acc[m][nf] = __builtin_amdgcn_mfma_f32_16x16x32_bf16(ah[m], bh, acc[m][nf], 0, 0, 0);
        acc[m][nf] = __builtin_amdgcn_mfma_f32_16x16x32_bf16(al[m], bh, acc[m][nf], 0, 0, 0);
        acc[m][nf] = __builtin_amdgcn_mfma_f32_16x16x32_bf16(ah[m], bl, acc[m][nf], 0, 0, 0);
      }
    }
  }
#pragma unroll
  for (int m = 0; m < 2; ++m)
#pragma unroll
    for (int nf = 0; nf < 4; ++nf) {
      int colx = nf * 16 + l15;
      int rowb = bm0 + m * 16 + lhi * 4;
#pragma unroll
      for (int j = 0; j < 4; ++j) {
        int row = rowb + j;
        if (row < NN) out[(size_t)row * CC + colx] = acc[m][nf][j];
      }
    }
}

extern "C" void kernel_launch(void* const* d_in, const int* in_sizes, int n_in,
                              void* d_out, int out_size, void* d_ws, size_t ws_size,
                              hipStream_t stream) {
  const float* xE = (const float*)d_in[0];
  const float* xH = (const float*)d_in[1];
  const float* xS = (const float*)d_in[2];
  const int* ei = (const int*)d_in[3];
  const float* W = (const float*)d_in[4];
  const float* b = (const float*)d_in[5];
  const float* cls = (const float*)d_in[6];
  float* out = (float*)d_out;

  char* ws = (char*)d_ws;
  size_t off = 0;
  auto alloc = [&](size_t bytes) {
    void* p = ws + off;
    off = (off + bytes + 255) & ~(size_t)255;
    return p;
  };
  unsigned short* h = (unsigned short*)alloc((size_t)NN * DD * 2);
  unsigned int* xnh = (unsigned int*)alloc((size_t)NN * 64 * 4);
  unsigned int* xnl = (unsigned int*)alloc((size_t)NN * 64 * 4);
  float* dinv = (float*)alloc((size_t)NN * 4);
  int* cnt = (int*)alloc((size_t)NN * 4);
  int* rowst = (int*)alloc((size_t)(NN + 1) * 4);
  int* cursor = (int*)alloc((size_t)NN * 4);
  int* col = (int*)alloc((size_t)EE * 4);
  unsigned short* Wth = (unsigned short*)alloc((size_t)DD * IND * 2);
  unsigned short* Wtl = (unsigned short*)alloc((size_t)DD * IND * 2);
  unsigned int* clsh = (unsigned int*)alloc((size_t)CC * 64 * 4);
  unsigned int* clsl = (unsigned int*)alloc((size_t)CC * 64 * 4);
  int* bsum = (int*)alloc(64 * 4);

  const int* esrc = ei;
  const int* edst = ei + EE;
  const int NB = (NN + 1023) / 1024;

  hipMemsetAsync(cnt, 0, (size_t)NN * 4, stream);
  k_count<<<(EE + 255) / 256, 256, 0, stream>>>(edst, cnt);
  k_scan1<<<NB, 1024, 0, stream>>>(cnt, rowst, dinv, bsum);
  k_scan2<<<1, 64, 0, stream>>>(bsum, rowst, NB);
  k_scan3<<<NB, 1024, 0, stream>>>(rowst, cursor, bsum);
  k_place<<<(EE + 255) / 256, 256, 0, stream>>>(esrc, edst, cursor, col);
  k_wprep<<<(IND * DD + 255) / 256, 256, 0, stream>>>(W, Wth, Wtl);
  k_cprep<<<1, 256, 0, stream>>>(cls, clsh, clsl);
  k_gemm<<<(NN + 31) / 32, 256, 0, stream>>>(xE, xH, xS, Wth, Wtl, dinv, h);
  k_aggn<<<(NN + 3) / 4, 256, 0, stream>>>(h, rowst, col, dinv, b, xnh, xnl);
  k_outg<<<(NN + 127) / 128, 256, 0, stream>>>((const unsigned short*)xnh,
                                               (const unsigned short*)xnl,
                                               (const unsigned short*)clsh,
                                               (const unsigned short*)clsl, out);
}